// Round 13
// baseline (511.281 us; speedup 1.0000x reference)
//
#include <hip/hip_runtime.h>

#define N_NODES  50000
#define N_EDGES  600000
#define DIM      128
#define N_GRAPHS 128
#define N_CLASSES 10
#define NB_SCAN  196          // ceil(50000/256)
#define LDSW     136          // padded LDS row width in ushorts
#define ZWORDS   1600032      // zero region: deg+cnt+epk (words)
#define NZB4     1563         // ceil(ZWORDS/4/256)

// NOTE: harness delivers ALL integer inputs as int32 (const int*).

typedef __bf16 bf16x8 __attribute__((ext_vector_type(8)));
typedef float  f32x4  __attribute__((ext_vector_type(4)));

__device__ inline unsigned short f2bf(float f) {      // RNE float->bf16
  union { float f; unsigned int i; } u; u.f = f;
  unsigned int r = u.i + 0x7fff + ((u.i >> 16) & 1);
  return (unsigned short)(r >> 16);
}
__device__ inline float bf2f(unsigned short s) {
  union { unsigned int i; float f; } u; u.i = ((unsigned int)s) << 16;
  return u.f;
}
__device__ inline bf16x8 pack8(float4 lo, float4 hi) {
  union { bf16x8 v; unsigned short s[8]; } u;
  u.s[0] = f2bf(lo.x); u.s[1] = f2bf(lo.y); u.s[2] = f2bf(lo.z); u.s[3] = f2bf(lo.w);
  u.s[4] = f2bf(hi.x); u.s[5] = f2bf(hi.y); u.s[6] = f2bf(hi.z); u.s[7] = f2bf(hi.w);
  return u.v;
}
// sign-extended byte -> float
__device__ inline float b2f0(unsigned u){ return (float)((int)(u<<24)>>24); }
__device__ inline float b2f1(unsigned u){ return (float)((int)(u<<16)>>24); }
__device__ inline float b2f2(unsigned u){ return (float)((int)(u<< 8)>>24); }
__device__ inline float b2f3(unsigned u){ return (float)((int) u     >>24); }

// ---------------- prep: zero CSR scratch (float4) + pack weights ---------------
// blocks [0,NZB4): zero deg+cnt+epk. blocks [NZB4, NZB4+64): pack 8 matrices
// into MFMA B-fragment layout, bf16.

__global__ __launch_bounds__(256) void k_prep(float4* __restrict__ z4,
                                              const float* __restrict__ W1,
                                              const float* __restrict__ R1,
                                              const float* __restrict__ Wc,
                                              const float* __restrict__ Rc,
                                              unsigned short* __restrict__ pk) {
  if (blockIdx.x < NZB4) {
    int i = blockIdx.x * 256 + threadIdx.x;
    if (i < ZWORDS / 4) z4[i] = make_float4(0.f, 0.f, 0.f, 0.f);
    return;
  }
  int pb = blockIdx.x - NZB4;           // 0..63
  int mm = pb >> 3, sub = pb & 7;
  const float* src = (mm == 0) ? W1
                   : (mm < 4)  ? Wc + (size_t)(mm - 1) * DIM * DIM
                   : (mm == 4) ? R1
                               : Rc + (size_t)(mm - 5) * DIM * DIM;
  int idx = sub * 256 + threadIdx.x;    // 0..2047 fragment-lane slots
  int lane = idx & 63;
  int kc   = (idx >> 6) & 3;
  int nt   = idx >> 8;
  int col  = nt * 16 + (lane & 15);
  int k0   = kc * 32 + (lane >> 4) * 8;
  unsigned short* dst = pk + (size_t)mm * 16384 + (size_t)idx * 8;
  ushort4 u;
  u.x = f2bf(src[(k0 + 0) * DIM + col]);
  u.y = f2bf(src[(k0 + 1) * DIM + col]);
  u.z = f2bf(src[(k0 + 2) * DIM + col]);
  u.w = f2bf(src[(k0 + 3) * DIM + col]);
  *(ushort4*)&dst[0] = u;
  u.x = f2bf(src[(k0 + 4) * DIM + col]);
  u.y = f2bf(src[(k0 + 5) * DIM + col]);
  u.z = f2bf(src[(k0 + 6) * DIM + col]);
  u.w = f2bf(src[(k0 + 7) * DIM + col]);
  *(ushort4*)&dst[4] = u;
}

// ---------------- CSR build (padded x4; packed int2{src, w_bits}) -------------
// Pad slots stay {0, 0.0f}: gathers hit row 0 (hot), weight 0 -> no contribution.

__global__ __launch_bounds__(256) void k_deg(const int* __restrict__ ei,
                                             int* __restrict__ deg) {
  int e = blockIdx.x * 256 + threadIdx.x;
  if (e < N_EDGES) atomicAdd(&deg[ei[N_EDGES + e]], 1);
}

__global__ __launch_bounds__(256) void k_dinvsum(const int* __restrict__ deg,
                                                 float* __restrict__ dinv,
                                                 int* __restrict__ bsum) {
  int i = blockIdx.x * 256 + threadIdx.x;
  int t = threadIdx.x;
  int d = (i < N_NODES) ? deg[i] : 0;
  if (i < N_NODES) dinv[i] = (d > 0) ? rsqrtf((float)d) : 0.f;
  int dp = (d + 3) & ~3;
  __shared__ int tmp[256];
  tmp[t] = dp;
  __syncthreads();
  for (int off = 128; off > 0; off >>= 1) {
    if (t < off) tmp[t] += tmp[t + off];
    __syncthreads();
  }
  if (t == 0) bsum[blockIdx.x] = tmp[0];
}

__global__ __launch_bounds__(256) void k_bscan(const int* __restrict__ bsum,
                                               int* __restrict__ boff,
                                               int* __restrict__ rowp) {
  int t = threadIdx.x;
  int v = (t < NB_SCAN) ? bsum[t] : 0;
  __shared__ int tmp[256];
  tmp[t] = v;
  __syncthreads();
  for (int off = 1; off < 256; off <<= 1) {
    int add = (t >= off) ? tmp[t - off] : 0;
    __syncthreads();
    tmp[t] += add;
    __syncthreads();
  }
  boff[t] = tmp[t] - v;          // exclusive
  if (t == 255) rowp[N_NODES] = tmp[255];   // total padded edge count
}

__global__ __launch_bounds__(256) void k_rowp(const int* __restrict__ deg,
                                              const int* __restrict__ boff,
                                              int* __restrict__ rowp) {
  int i = blockIdx.x * 256 + threadIdx.x;
  int t = threadIdx.x;
  int dp = (i < N_NODES) ? ((deg[i] + 3) & ~3) : 0;
  __shared__ int tmp[256];
  tmp[t] = dp;
  __syncthreads();
  for (int off = 1; off < 256; off <<= 1) {
    int add = (t >= off) ? tmp[t - off] : 0;
    __syncthreads();
    tmp[t] += add;
    __syncthreads();
  }
  if (i < N_NODES) rowp[i] = boff[blockIdx.x] + tmp[t] - dp;  // exclusive
}

__global__ __launch_bounds__(256) void k_fill(const int* __restrict__ ei,
                                              const int* __restrict__ rowp,
                                              int* __restrict__ cnt,
                                              const float* __restrict__ dinv,
                                              int2* __restrict__ epk) {
  int e = blockIdx.x * 256 + threadIdx.x;
  if (e < N_EDGES) {
    int s = ei[e];
    int d = ei[N_EDGES + e];
    int p = rowp[d] + atomicAdd(&cnt[d], 1);
    epk[p] = make_int2(s, __float_as_int(dinv[s] * dinv[d]));
  }
}

// ---------------- layer-0 MFMA dual GEMM -------------------------------------
// h0q = int8 rowmax-quant(x@W1), h0sc = row scales; skipb = bf16(x@R1 + b1).
// Layouts (HW-verified): A[m=lane&15][k=(lane>>4)*8+j]; D col=lane&15,
// row=(lane>>4)*4+reg.

__global__ __launch_bounds__(256) void k_gemm0(const float* __restrict__ xf,
                                               const unsigned short* __restrict__ pkW,
                                               const unsigned short* __restrict__ pkR,
                                               const float* __restrict__ bv,
                                               signed char* __restrict__ hq,
                                               float* __restrict__ hsc,
                                               unsigned short* __restrict__ skipb) {
  const int tid  = threadIdx.x;
  const int wave = tid >> 6, lane = tid & 63;
  const int m = lane & 15, q = lane >> 4;
  const int rbase = blockIdx.x * 64 + wave * 16;
  const int arow  = rbase + m;
  const bool aok  = arow < N_NODES;

  bf16x8 a[4];
#pragma unroll
  for (int kc = 0; kc < 4; ++kc) {
    float4 lo = make_float4(0.f, 0.f, 0.f, 0.f);
    float4 hi = make_float4(0.f, 0.f, 0.f, 0.f);
    if (aok) {
      lo = *(const float4*)&xf[arow * DIM + kc * 32 + q * 8];
      hi = *(const float4*)&xf[arow * DIM + kc * 32 + q * 8 + 4];
    }
    a[kc] = pack8(lo, hi);
  }

  f32x4 acc[16];
#pragma unroll
  for (int t = 0; t < 16; ++t) acc[t] = (f32x4){0.f, 0.f, 0.f, 0.f};

#pragma unroll
  for (int nt = 0; nt < 8; ++nt) {
    const unsigned short* pw = pkW + ((size_t)(nt * 4) * 64 + lane) * 8;
    const unsigned short* pr = pkR + ((size_t)(nt * 4) * 64 + lane) * 8;
#pragma unroll
    for (int kc = 0; kc < 4; ++kc) {
      bf16x8 bW = *(const bf16x8*)(pw + (size_t)kc * 64 * 8);
      acc[nt] = __builtin_amdgcn_mfma_f32_16x16x32_bf16(a[kc], bW, acc[nt], 0, 0, 0);
    }
#pragma unroll
    for (int kc = 0; kc < 4; ++kc) {
      bf16x8 bR = *(const bf16x8*)(pr + (size_t)kc * 64 * 8);
      acc[8 + nt] = __builtin_amdgcn_mfma_f32_16x16x32_bf16(a[kc], bR, acc[8 + nt], 0, 0, 0);
    }
  }

  // W-path epilogue: per-row amax (shfl over the 16-lane m-group), int8 quant
  float am[4], inv[4];
#pragma unroll
  for (int rg = 0; rg < 4; ++rg) {
    float v = 0.f;
#pragma unroll
    for (int nt = 0; nt < 8; ++nt) v = fmaxf(v, fabsf(acc[nt][rg]));
    am[rg] = v;
  }
#pragma unroll
  for (int mask = 1; mask <= 8; mask <<= 1) {
#pragma unroll
    for (int rg = 0; rg < 4; ++rg)
      am[rg] = fmaxf(am[rg], __shfl_xor(am[rg], mask, 64));
  }
#pragma unroll
  for (int rg = 0; rg < 4; ++rg) inv[rg] = (am[rg] > 0.f) ? 127.f / am[rg] : 0.f;
  if (m == 0) {
#pragma unroll
    for (int rg = 0; rg < 4; ++rg) {
      int row = rbase + q * 4 + rg;
      if (row < N_NODES) hsc[row] = am[rg] * (1.f / 127.f);
    }
  }
#pragma unroll
  for (int nt = 0; nt < 8; ++nt) {
    int col = nt * 16 + m;
#pragma unroll
    for (int rg = 0; rg < 4; ++rg) {
      int row = rbase + q * 4 + rg;
      if (row < N_NODES)
        hq[row * DIM + col] = (signed char)__float2int_rn(acc[nt][rg] * inv[rg]);
    }
  }
  // R-path epilogue
#pragma unroll
  for (int nt = 0; nt < 8; ++nt) {
    int col = nt * 16 + m;
    float bias = bv[col];
#pragma unroll
    for (int rg = 0; rg < 4; ++rg) {
      int row = rbase + q * 4 + rg;
      if (row < N_NODES) skipb[row * DIM + col] = f2bf(acc[8 + nt][rg] + bias);
    }
  }
}

// ---------------- fused agg(l) + gemm(l+1), 256 threads -----------------------
// Phase A: act = relu(skipb + sum_e w*sc[src]*hq[src]) -> LDS bf16.
//   int8 rows = 128B (2 cache lines vs bf16's 4): halves the L2-miss fill
//   traffic that R10-R12 showed to be the gather's binding constraint.
// Phase B: MFMA gemm; hout int8+scale, skip' bf16 (fp32 for LAST).

template<bool LAST>
__global__ __launch_bounds__(256) void k_aggemm(const signed char* __restrict__ hq,
                                                const float* __restrict__ hsc,
                                                const int* __restrict__ rowp,
                                                const int2* __restrict__ epk,
                                                const unsigned short* __restrict__ pkW,
                                                const unsigned short* __restrict__ pkR,
                                                const float* __restrict__ bv,
                                                signed char* __restrict__ hoq,
                                                float* __restrict__ hosc,
                                                unsigned short* __restrict__ skipb,
                                                float* __restrict__ skipf) {
  __shared__ unsigned short xs[64 * LDSW];
  const int tid = threadIdx.x;
  const int row0 = blockIdx.x * 64;

  // ---- phase A: 8 half-waves x 8 rounds ----
  {
    int hw = tid >> 5;
    int l4 = (tid & 31) * 4;
    for (int rnd = 0; rnd < 8; ++rnd) {
      int n = row0 + rnd * 8 + hw;
      float4 acc = make_float4(0.f, 0.f, 0.f, 0.f);
      if (n < N_NODES) {
        ushort4 s = *(const ushort4*)&skipb[n * DIM + l4];
        acc = make_float4(bf2f(s.x), bf2f(s.y), bf2f(s.z), bf2f(s.w));
        int e0 = rowp[n], e1 = rowp[n + 1];
        for (int e = e0; e < e1; e += 4) {
          int4 p0 = *(const int4*)&epk[e];
          int4 p1 = *(const int4*)&epk[e + 2];
          unsigned g0 = *(const unsigned*)&hq[p0.x * DIM + l4];
          unsigned g1 = *(const unsigned*)&hq[p0.z * DIM + l4];
          unsigned g2 = *(const unsigned*)&hq[p1.x * DIM + l4];
          unsigned g3 = *(const unsigned*)&hq[p1.z * DIM + l4];
          float w0 = __int_as_float(p0.y) * hsc[p0.x];
          float w1 = __int_as_float(p0.w) * hsc[p0.z];
          float w2 = __int_as_float(p1.y) * hsc[p1.x];
          float w3 = __int_as_float(p1.w) * hsc[p1.z];
          acc.x = fmaf(w0, b2f0(g0), fmaf(w1, b2f0(g1), fmaf(w2, b2f0(g2), fmaf(w3, b2f0(g3), acc.x))));
          acc.y = fmaf(w0, b2f1(g0), fmaf(w1, b2f1(g1), fmaf(w2, b2f1(g2), fmaf(w3, b2f1(g3), acc.y))));
          acc.z = fmaf(w0, b2f2(g0), fmaf(w1, b2f2(g1), fmaf(w2, b2f2(g2), fmaf(w3, b2f2(g3), acc.z))));
          acc.w = fmaf(w0, b2f3(g0), fmaf(w1, b2f3(g1), fmaf(w2, b2f3(g2), fmaf(w3, b2f3(g3), acc.w))));
        }
        acc.x = fmaxf(acc.x, 0.f);
        acc.y = fmaxf(acc.y, 0.f);
        acc.z = fmaxf(acc.z, 0.f);
        acc.w = fmaxf(acc.w, 0.f);
      }
      int r = rnd * 8 + hw;
      ushort4 o;
      o.x = f2bf(acc.x); o.y = f2bf(acc.y); o.z = f2bf(acc.z); o.w = f2bf(acc.w);
      *(ushort4*)&xs[r * LDSW + l4] = o;
    }
  }
  __syncthreads();

  // ---- phase B ----
  const int wave = tid >> 6, lane = tid & 63;
  const int m = lane & 15, q = lane >> 4;
  const int rbase = row0 + wave * 16;

  bf16x8 a[4];
#pragma unroll
  for (int kc = 0; kc < 4; ++kc)
    a[kc] = *(const bf16x8*)&xs[(wave * 16 + m) * LDSW + kc * 32 + q * 8];

  f32x4 acc[16];
#pragma unroll
  for (int t = 0; t < 16; ++t) acc[t] = (f32x4){0.f, 0.f, 0.f, 0.f};

#pragma unroll
  for (int nt = 0; nt < 8; ++nt) {
    const unsigned short* pw = pkW + ((size_t)(nt * 4) * 64 + lane) * 8;
    const unsigned short* pr = pkR + ((size_t)(nt * 4) * 64 + lane) * 8;
#pragma unroll
    for (int kc = 0; kc < 4; ++kc) {
      bf16x8 bW = *(const bf16x8*)(pw + (size_t)kc * 64 * 8);
      acc[nt] = __builtin_amdgcn_mfma_f32_16x16x32_bf16(a[kc], bW, acc[nt], 0, 0, 0);
    }
#pragma unroll
    for (int kc = 0; kc < 4; ++kc) {
      bf16x8 bR = *(const bf16x8*)(pr + (size_t)kc * 64 * 8);
      acc[8 + nt] = __builtin_amdgcn_mfma_f32_16x16x32_bf16(a[kc], bR, acc[8 + nt], 0, 0, 0);
    }
  }

  // W-path: int8 rowmax quant
  float am[4], inv[4];
#pragma unroll
  for (int rg = 0; rg < 4; ++rg) {
    float v = 0.f;
#pragma unroll
    for (int nt = 0; nt < 8; ++nt) v = fmaxf(v, fabsf(acc[nt][rg]));
    am[rg] = v;
  }
#pragma unroll
  for (int mask = 1; mask <= 8; mask <<= 1) {
#pragma unroll
    for (int rg = 0; rg < 4; ++rg)
      am[rg] = fmaxf(am[rg], __shfl_xor(am[rg], mask, 64));
  }
#pragma unroll
  for (int rg = 0; rg < 4; ++rg) inv[rg] = (am[rg] > 0.f) ? 127.f / am[rg] : 0.f;
  if (m == 0) {
#pragma unroll
    for (int rg = 0; rg < 4; ++rg) {
      int row = rbase + q * 4 + rg;
      if (row < N_NODES) hosc[row] = am[rg] * (1.f / 127.f);
    }
  }
#pragma unroll
  for (int nt = 0; nt < 8; ++nt) {
    int col = nt * 16 + m;
#pragma unroll
    for (int rg = 0; rg < 4; ++rg) {
      int row = rbase + q * 4 + rg;
      if (row < N_NODES)
        hoq[row * DIM + col] = (signed char)__float2int_rn(acc[nt][rg] * inv[rg]);
    }
  }
  // R-path
#pragma unroll
  for (int nt = 0; nt < 8; ++nt) {
    int col = nt * 16 + m;
    float bias = bv[col];
#pragma unroll
    for (int rg = 0; rg < 4; ++rg) {
      int row = rbase + q * 4 + rg;
      if (row < N_NODES) {
        float v = acc[8 + nt][rg] + bias;
        if (LAST) skipf[row * DIM + col] = v;
        else      skipb[row * DIM + col] = f2bf(v);
      }
    }
  }
}

// ---------------- final aggregation: dlast = relu(dlast + gather(hq)) ---------

__global__ __launch_bounds__(256) void k_aggF(const signed char* __restrict__ hq,
                                              const float* __restrict__ hsc,
                                              const int* __restrict__ rowp,
                                              const int2* __restrict__ epk,
                                              float* __restrict__ actf) {
  int n = blockIdx.x * 8 + (threadIdx.x >> 5);
  if (n >= N_NODES) return;
  int l4 = (threadIdx.x & 31) * 4;
  float4 acc = *(const float4*)&actf[n * DIM + l4];
  int e0 = rowp[n], e1 = rowp[n + 1];
  for (int e = e0; e < e1; e += 4) {
    int4 p0 = *(const int4*)&epk[e];
    int4 p1 = *(const int4*)&epk[e + 2];
    unsigned g0 = *(const unsigned*)&hq[p0.x * DIM + l4];
    unsigned g1 = *(const unsigned*)&hq[p0.z * DIM + l4];
    unsigned g2 = *(const unsigned*)&hq[p1.x * DIM + l4];
    unsigned g3 = *(const unsigned*)&hq[p1.z * DIM + l4];
    float w0 = __int_as_float(p0.y) * hsc[p0.x];
    float w1 = __int_as_float(p0.w) * hsc[p0.z];
    float w2 = __int_as_float(p1.y) * hsc[p1.x];
    float w3 = __int_as_float(p1.w) * hsc[p1.z];
    acc.x = fmaf(w0, b2f0(g0), fmaf(w1, b2f0(g1), fmaf(w2, b2f0(g2), fmaf(w3, b2f0(g3), acc.x))));
    acc.y = fmaf(w0, b2f1(g0), fmaf(w1, b2f1(g1), fmaf(w2, b2f1(g2), fmaf(w3, b2f1(g3), acc.y))));
    acc.z = fmaf(w0, b2f2(g0), fmaf(w1, b2f2(g1), fmaf(w2, b2f2(g2), fmaf(w3, b2f2(g3), acc.z))));
    acc.w = fmaf(w0, b2f3(g0), fmaf(w1, b2f3(g1), fmaf(w2, b2f3(g2), fmaf(w3, b2f3(g3), acc.w))));
  }
  acc.x = fmaxf(acc.x, 0.f);
  acc.y = fmaxf(acc.y, 0.f);
  acc.z = fmaxf(acc.z, 0.f);
  acc.w = fmaxf(acc.w, 0.f);
  *(float4*)&actf[n * DIM + l4] = acc;
}

// ---------------- global mean pool: block per graph, batch is SORTED ----------

__global__ __launch_bounds__(1024) void k_pool2(const float* __restrict__ h,
                                                const int* __restrict__ batch,
                                                float* __restrict__ pooled) {
  int g = blockIdx.x;
  int t = threadIdx.x;
  __shared__ int sb[2];
  if (t < 2) {
    int target = g + t;                 // lower_bound(batch, target)
    int lo = 0, hi = N_NODES;
    while (lo < hi) {
      int mid = (lo + hi) >> 1;
      if (batch[mid] < target) lo = mid + 1; else hi = mid;
    }
    sb[t] = lo;
  }
  __syncthreads();
  int start = sb[0], end = sb[1];
  int c = t & 127, rg = t >> 7;         // 8 row groups
  float acc = 0.f;
  for (int r = start + rg; r < end; r += 8) acc += h[r * DIM + c];
  __shared__ float sp[8][DIM];
  sp[rg][c] = acc;
  __syncthreads();
  if (rg == 0) {
    float tot = acc;
#pragma unroll
    for (int i = 1; i < 8; ++i) tot += sp[i][c];
    float cnt = fmaxf((float)(end - start), 1.f);
    pooled[g * DIM + c] = tot / cnt;
  }
}

// ---------------- MLP head ----------------

__global__ __launch_bounds__(128) void k_mlp1(const float* __restrict__ pooled,
                                              const float* __restrict__ w,
                                              const float* __restrict__ bias,
                                              float* __restrict__ g1) {
  int g = blockIdx.x, t = threadIdx.x;
  __shared__ float sp[DIM];
  sp[t] = pooled[g * DIM + t];
  __syncthreads();
  float acc = bias[t];
#pragma unroll 4
  for (int k = 0; k < DIM; ++k) acc = fmaf(sp[k], w[k * DIM + t], acc);
  g1[g * DIM + t] = fmaxf(acc, 0.f);
}

__global__ __launch_bounds__(128) void k_mlp2(const float* __restrict__ g1,
                                              const float* __restrict__ w,
                                              const float* __restrict__ bias,
                                              float* __restrict__ out) {
  int g = threadIdx.x;   // one thread per graph
  float l[N_CLASSES];
#pragma unroll
  for (int c = 0; c < N_CLASSES; ++c) l[c] = bias[c];
  for (int k = 0; k < DIM; ++k) {
    float gv = g1[g * DIM + k];
#pragma unroll
    for (int c = 0; c < N_CLASSES; ++c) l[c] = fmaf(gv, w[k * N_CLASSES + c], l[c]);
  }
  float m = l[0];
#pragma unroll
  for (int c = 1; c < N_CLASSES; ++c) m = fmaxf(m, l[c]);
  float s = 0.f;
#pragma unroll
  for (int c = 0; c < N_CLASSES; ++c) s += expf(l[c] - m);
  float lse = logf(s) + m;
#pragma unroll
  for (int c = 0; c < N_CLASSES; ++c) out[g * N_CLASSES + c] = l[c] - lse;
}

// ---------------- launch ----------------

extern "C" void kernel_launch(void* const* d_in, const int* in_sizes, int n_in,
                              void* d_out, int out_size, void* d_ws, size_t ws_size,
                              hipStream_t stream) {
  const float* x     = (const float*)d_in[0];
  const int* ei      = (const int*)d_in[1];     // int32 on device (harness)
  const int* batch   = (const int*)d_in[2];     // int32 on device (harness)
  const float* W1  = (const float*)d_in[3];
  const float* R1  = (const float*)d_in[4];
  const float* b1  = (const float*)d_in[5];
  const float* Wc  = (const float*)d_in[6];
  const float* Rc  = (const float*)d_in[7];
  const float* bc  = (const float*)d_in[8];
  const float* l1w = (const float*)d_in[9];
  const float* l1b = (const float*)d_in[10];
  const float* l2w = (const float*)d_in[11];
  const float* l2b = (const float*)d_in[12];

  float* out   = (float*)d_out;
  float* dlast = out + N_GRAPHS * N_CLASSES;   // 'last' region (fp32 layer-4 buffer)

  // workspace layout (float-word offsets), ~33.2 MB total:
  //   0         h0q   (1,601,536 w : int8 50048x128)
  //   1601536   h1q   (1,601,536 w)
  //   3203072   skipb (3,203,072 w : bf16 50048x128)
  //   6406144   deg   (50,000)   -- zero region start
  //   6456144   cnt   (50,000)
  //   6506144   epk   (1,500,032 w = 750,016 int2)  -- zero end (1,600,032 w)
  //   8006176   dinv  (50,016)
  //   8056192   rowp  (50,016)
  //   8106208   h0sc  (50,016)
  //   8156224   h1sc  (50,016)
  //   8206240   pooled(16,384)
  //   8222624   g1    (16,384)
  //   8239008   pk    (65,536 w)
  //   8304544   bsum  (256)
  //   8304800   boff  (256)
  float* ws = (float*)d_ws;
  signed char*    h0q   = (signed char*)ws;
  signed char*    h1q   = (signed char*)(ws + 1601536);
  unsigned short* skipb = (unsigned short*)(ws + 3203072);
  int*   deg   = (int*)(ws + 6406144);
  int*   cnt   = (int*)(ws + 6456144);
  int2*  epk   = (int2*)(ws + 6506144);
  float* dinv  = ws + 8006176;
  int*   rowp  = (int*)(ws + 8056192);
  float* h0sc  = ws + 8106208;
  float* h1sc  = ws + 8156224;
  float* pooled= ws + 8206240;
  float* g1    = ws + 8222624;
  unsigned short* pk = (unsigned short*)(ws + 8239008);
  int*   bsum  = (int*)(ws + 8304544);
  int*   boff  = (int*)(ws + 8304800);

  // CSR build (runs every launch; ws is re-poisoned by the harness)
  k_prep<<<NZB4 + 64, 256, 0, stream>>>((float4*)(ws + 6406144), W1, R1, Wc, Rc, pk);
  k_deg <<<(N_EDGES + 255) / 256, 256, 0, stream>>>(ei, deg);
  k_dinvsum<<<NB_SCAN, 256, 0, stream>>>(deg, dinv, bsum);
  k_bscan<<<1, 256, 0, stream>>>(bsum, boff, rowp);
  k_rowp<<<NB_SCAN, 256, 0, stream>>>(deg, boff, rowp);
  k_fill<<<(N_EDGES + 255) / 256, 256, 0, stream>>>(ei, rowp, cnt, dinv, epk);

  const int NGB = (N_NODES + 63) / 64;    // 782
  const int NAB = (N_NODES + 7) / 8;      // 6250

  // layer 1 gemm: x (fp32) -> h0q/h0sc, skipb
  k_gemm0<<<NGB, 256, 0, stream>>>(x, pk + 0 * 16384, pk + 4 * 16384, b1,
                                   h0q, h0sc, skipb);
  // fused [agg1 + gemm2]: h0 -> h1
  k_aggemm<false><<<NGB, 256, 0, stream>>>(h0q, h0sc, rowp, epk,
      pk + 1 * 16384, pk + 5 * 16384, bc + 0 * DIM, h1q, h1sc, skipb, nullptr);
  // fused [agg2 + gemm3]: h1 -> h0
  k_aggemm<false><<<NGB, 256, 0, stream>>>(h1q, h1sc, rowp, epk,
      pk + 2 * 16384, pk + 6 * 16384, bc + 1 * DIM, h0q, h0sc, skipb, nullptr);
  // fused [agg3 + gemm4]: h0 -> h1, skip -> dlast (fp32)
  k_aggemm<true><<<NGB, 256, 0, stream>>>(h0q, h0sc, rowp, epk,
      pk + 3 * 16384, pk + 7 * 16384, bc + 2 * DIM, h1q, h1sc, skipb, dlast);
  // final agg4: dlast = relu(dlast + gather(h1))
  k_aggF<<<NAB, 256, 0, stream>>>(h1q, h1sc, rowp, epk, dlast);

  k_pool2<<<N_GRAPHS, 1024, 0, stream>>>(dlast, batch, pooled);
  k_mlp1<<<N_GRAPHS, 128, 0, stream>>>(pooled, l1w, l1b, g1);
  k_mlp2<<<1, N_GRAPHS, 0, stream>>>(g1, l2w, l2b, out);
}

// Round 14
// 394.161 us; speedup vs baseline: 1.2971x; 1.2971x over previous
//
#include <hip/hip_runtime.h>

#define N_NODES  50000
#define N_EDGES  600000
#define DIM      128
#define N_GRAPHS 128
#define N_CLASSES 10
#define NB_SCAN  196          // ceil(50000/256)
#define LDSW     136          // padded LDS row width in ushorts
#define ZWORDS   1700000      // zero region: deg+cnt+epk (words)
#define NZB4     1661         // ceil(ZWORDS/4/256)

// NOTE: harness delivers ALL integer inputs as int32 (const int*).

typedef __bf16 bf16x8 __attribute__((ext_vector_type(8)));
typedef float  f32x4  __attribute__((ext_vector_type(4)));

__device__ inline unsigned short f2bf(float f) {      // RNE float->bf16
  union { float f; unsigned int i; } u; u.f = f;
  unsigned int r = u.i + 0x7fff + ((u.i >> 16) & 1);
  return (unsigned short)(r >> 16);
}
__device__ inline float bf2f(unsigned short s) {
  union { unsigned int i; float f; } u; u.i = ((unsigned int)s) << 16;
  return u.f;
}
__device__ inline bf16x8 pack8(float4 lo, float4 hi) {
  union { bf16x8 v; unsigned short s[8]; } u;
  u.s[0] = f2bf(lo.x); u.s[1] = f2bf(lo.y); u.s[2] = f2bf(lo.z); u.s[3] = f2bf(lo.w);
  u.s[4] = f2bf(hi.x); u.s[5] = f2bf(hi.y); u.s[6] = f2bf(hi.z); u.s[7] = f2bf(hi.w);
  return u.v;
}

// ---------------- prep: zero CSR scratch (float4) + pack weights ---------------

__global__ __launch_bounds__(256) void k_prep(float4* __restrict__ z4,
                                              const float* __restrict__ W1,
                                              const float* __restrict__ R1,
                                              const float* __restrict__ Wc,
                                              const float* __restrict__ Rc,
                                              unsigned short* __restrict__ pk) {
  if (blockIdx.x < NZB4) {
    int i = blockIdx.x * 256 + threadIdx.x;
    if (i < ZWORDS / 4) z4[i] = make_float4(0.f, 0.f, 0.f, 0.f);
    return;
  }
  int pb = blockIdx.x - NZB4;           // 0..63
  int mm = pb >> 3, sub = pb & 7;
  const float* src = (mm == 0) ? W1
                   : (mm < 4)  ? Wc + (size_t)(mm - 1) * DIM * DIM
                   : (mm == 4) ? R1
                               : Rc + (size_t)(mm - 5) * DIM * DIM;
  int idx = sub * 256 + threadIdx.x;    // 0..2047 fragment-lane slots
  int lane = idx & 63;
  int kc   = (idx >> 6) & 3;
  int nt   = idx >> 8;
  int col  = nt * 16 + (lane & 15);
  int k0   = kc * 32 + (lane >> 4) * 8;
  unsigned short* dst = pk + (size_t)mm * 16384 + (size_t)idx * 8;
  ushort4 u;
  u.x = f2bf(src[(k0 + 0) * DIM + col]);
  u.y = f2bf(src[(k0 + 1) * DIM + col]);
  u.z = f2bf(src[(k0 + 2) * DIM + col]);
  u.w = f2bf(src[(k0 + 3) * DIM + col]);
  *(ushort4*)&dst[0] = u;
  u.x = f2bf(src[(k0 + 4) * DIM + col]);
  u.y = f2bf(src[(k0 + 5) * DIM + col]);
  u.z = f2bf(src[(k0 + 6) * DIM + col]);
  u.w = f2bf(src[(k0 + 7) * DIM + col]);
  *(ushort4*)&dst[4] = u;
}

// ---------------- CSR build (padded x4; packed int2{src, w_bits}) -------------
// Pad slots stay {0, 0.0f}: gathers hit row 0 (hot), weight 0 -> contribute 0.

__global__ __launch_bounds__(256) void k_deg(const int* __restrict__ ei,
                                             int* __restrict__ deg) {
  int e = blockIdx.x * 256 + threadIdx.x;
  if (e < N_EDGES) atomicAdd(&deg[ei[N_EDGES + e]], 1);
}

__global__ __launch_bounds__(256) void k_dinvsum(const int* __restrict__ deg,
                                                 float* __restrict__ dinv,
                                                 int* __restrict__ bsum) {
  int i = blockIdx.x * 256 + threadIdx.x;
  int t = threadIdx.x;
  int d = (i < N_NODES) ? deg[i] : 0;
  if (i < N_NODES) dinv[i] = (d > 0) ? rsqrtf((float)d) : 0.f;
  int dp = (d + 3) & ~3;
  __shared__ int tmp[256];
  tmp[t] = dp;
  __syncthreads();
  for (int off = 128; off > 0; off >>= 1) {
    if (t < off) tmp[t] += tmp[t + off];
    __syncthreads();
  }
  if (t == 0) bsum[blockIdx.x] = tmp[0];
}

__global__ __launch_bounds__(256) void k_bscan(const int* __restrict__ bsum,
                                               int* __restrict__ boff,
                                               int* __restrict__ rowp) {
  int t = threadIdx.x;
  int v = (t < NB_SCAN) ? bsum[t] : 0;
  __shared__ int tmp[256];
  tmp[t] = v;
  __syncthreads();
  for (int off = 1; off < 256; off <<= 1) {
    int add = (t >= off) ? tmp[t - off] : 0;
    __syncthreads();
    tmp[t] += add;
    __syncthreads();
  }
  boff[t] = tmp[t] - v;          // exclusive
  if (t == 255) rowp[N_NODES] = tmp[255];   // total padded edge count
}

__global__ __launch_bounds__(256) void k_rowp(const int* __restrict__ deg,
                                              const int* __restrict__ boff,
                                              int* __restrict__ rowp) {
  int i = blockIdx.x * 256 + threadIdx.x;
  int t = threadIdx.x;
  int dp = (i < N_NODES) ? ((deg[i] + 3) & ~3) : 0;
  __shared__ int tmp[256];
  tmp[t] = dp;
  __syncthreads();
  for (int off = 1; off < 256; off <<= 1) {
    int add = (t >= off) ? tmp[t - off] : 0;
    __syncthreads();
    tmp[t] += add;
    __syncthreads();
  }
  if (i < N_NODES) rowp[i] = boff[blockIdx.x] + tmp[t] - dp;  // exclusive
}

__global__ __launch_bounds__(256) void k_fill(const int* __restrict__ ei,
                                              const int* __restrict__ rowp,
                                              int* __restrict__ cnt,
                                              const float* __restrict__ dinv,
                                              int2* __restrict__ epk) {
  int e = blockIdx.x * 256 + threadIdx.x;
  if (e < N_EDGES) {
    int s = ei[e];
    int d = ei[N_EDGES + e];
    int p = rowp[d] + atomicAdd(&cnt[d], 1);
    epk[p] = make_int2(s, __float_as_int(dinv[s] * dinv[d]));  // one 8B store
  }
}

// ---------------- layer-0 MFMA dual GEMM: h0 = bf16(x@W1) ; skipb = x@R1+b1 ---
// Layouts (HW-verified): A[m=lane&15][k=(lane>>4)*8+j]; D col=lane&15,
// row=(lane>>4)*4+reg.

__global__ __launch_bounds__(256) void k_gemm0(const float* __restrict__ xf,
                                               const unsigned short* __restrict__ pkW,
                                               const unsigned short* __restrict__ pkR,
                                               const float* __restrict__ bv,
                                               unsigned short* __restrict__ hwb,
                                               unsigned short* __restrict__ skipb) {
  const int tid  = threadIdx.x;
  const int wave = tid >> 6, lane = tid & 63;
  const int m = lane & 15, q = lane >> 4;
  const int rbase = blockIdx.x * 64 + wave * 16;
  const int arow  = rbase + m;
  const bool aok  = arow < N_NODES;

  bf16x8 a[4];
#pragma unroll
  for (int kc = 0; kc < 4; ++kc) {
    float4 lo = make_float4(0.f, 0.f, 0.f, 0.f);
    float4 hi = make_float4(0.f, 0.f, 0.f, 0.f);
    if (aok) {
      lo = *(const float4*)&xf[arow * DIM + kc * 32 + q * 8];
      hi = *(const float4*)&xf[arow * DIM + kc * 32 + q * 8 + 4];
    }
    a[kc] = pack8(lo, hi);
  }

  f32x4 acc[16];
#pragma unroll
  for (int t = 0; t < 16; ++t) acc[t] = (f32x4){0.f, 0.f, 0.f, 0.f};

#pragma unroll
  for (int nt = 0; nt < 8; ++nt) {
    const unsigned short* pw = pkW + ((size_t)(nt * 4) * 64 + lane) * 8;
    const unsigned short* pr = pkR + ((size_t)(nt * 4) * 64 + lane) * 8;
#pragma unroll
    for (int kc = 0; kc < 4; ++kc) {
      bf16x8 bW = *(const bf16x8*)(pw + (size_t)kc * 64 * 8);
      acc[nt] = __builtin_amdgcn_mfma_f32_16x16x32_bf16(a[kc], bW, acc[nt], 0, 0, 0);
    }
#pragma unroll
    for (int kc = 0; kc < 4; ++kc) {
      bf16x8 bR = *(const bf16x8*)(pr + (size_t)kc * 64 * 8);
      acc[8 + nt] = __builtin_amdgcn_mfma_f32_16x16x32_bf16(a[kc], bR, acc[8 + nt], 0, 0, 0);
    }
  }

#pragma unroll
  for (int nt = 0; nt < 8; ++nt) {
    int col = nt * 16 + m;
    float bias = bv[col];
#pragma unroll
    for (int rg = 0; rg < 4; ++rg) {
      int row = rbase + q * 4 + rg;
      if (row < N_NODES) {
        hwb[row * DIM + col]   = f2bf(acc[nt][rg]);
        skipb[row * DIM + col] = f2bf(acc[8 + nt][rg] + bias);
      }
    }
  }
}

// ---------------- fused agg(l) + gemm(l+1), BARRIER-FREE ----------------------
// R10-R13 evidence: gather phase is convoy-bound (all 8 half-waves must clear
// the barrier before any MFMA; achieved occupancy capped ~27% regardless of
// wave count). Fix: wave w aggregates ITS OWN 16 rows into its own LDS region
// (2 half-waves x 8 rounds) -> zero cross-wave deps -> NO __syncthreads.
// Each wave flows gather->MFMA independently; MFMA/VALU pipes overlap across
// waves (m114).

template<bool LAST>
__global__ __launch_bounds__(256) void k_aggemm(const unsigned short* __restrict__ hin,
                                                const int* __restrict__ rowp,
                                                const int2* __restrict__ epk,
                                                const unsigned short* __restrict__ pkW,
                                                const unsigned short* __restrict__ pkR,
                                                const float* __restrict__ bv,
                                                unsigned short* __restrict__ hout,
                                                unsigned short* __restrict__ skipb,
                                                float* __restrict__ skipf) {
  __shared__ unsigned short xs[64 * LDSW];
  const int tid = threadIdx.x;
  const int row0 = blockIdx.x * 64;
  const int wave = tid >> 6, lane = tid & 63;

  // ---- phase A (wave-local): half-wave h of wave w does rows w*16+rnd*2+h ----
  {
    int h  = (tid >> 5) & 1;
    int l4 = (tid & 31) * 4;
    for (int rnd = 0; rnd < 8; ++rnd) {
      int r = wave * 16 + rnd * 2 + h;
      int n = row0 + r;
      float4 acc = make_float4(0.f, 0.f, 0.f, 0.f);
      if (n < N_NODES) {
        int e0 = rowp[n], e1 = rowp[n + 1];
        for (int e = e0; e < e1; e += 4) {
          int4 p0 = *(const int4*)&epk[e];
          int4 p1 = *(const int4*)&epk[e + 2];
          ushort4 u0 = *(const ushort4*)&hin[p0.x * DIM + l4];
          ushort4 u1 = *(const ushort4*)&hin[p0.z * DIM + l4];
          ushort4 u2 = *(const ushort4*)&hin[p1.x * DIM + l4];
          ushort4 u3 = *(const ushort4*)&hin[p1.z * DIM + l4];
          float w0 = __int_as_float(p0.y), w1 = __int_as_float(p0.w);
          float w2 = __int_as_float(p1.y), w3 = __int_as_float(p1.w);
          acc.x = fmaf(w0, bf2f(u0.x), fmaf(w1, bf2f(u1.x), fmaf(w2, bf2f(u2.x), fmaf(w3, bf2f(u3.x), acc.x))));
          acc.y = fmaf(w0, bf2f(u0.y), fmaf(w1, bf2f(u1.y), fmaf(w2, bf2f(u2.y), fmaf(w3, bf2f(u3.y), acc.y))));
          acc.z = fmaf(w0, bf2f(u0.z), fmaf(w1, bf2f(u1.z), fmaf(w2, bf2f(u2.z), fmaf(w3, bf2f(u3.z), acc.z))));
          acc.w = fmaf(w0, bf2f(u0.w), fmaf(w1, bf2f(u1.w), fmaf(w2, bf2f(u2.w), fmaf(w3, bf2f(u3.w), acc.w))));
        }
        ushort4 s = *(const ushort4*)&skipb[n * DIM + l4];
        acc.x = fmaxf(acc.x + bf2f(s.x), 0.f);
        acc.y = fmaxf(acc.y + bf2f(s.y), 0.f);
        acc.z = fmaxf(acc.z + bf2f(s.z), 0.f);
        acc.w = fmaxf(acc.w + bf2f(s.w), 0.f);
      }
      ushort4 o;
      o.x = f2bf(acc.x); o.y = f2bf(acc.y); o.z = f2bf(acc.z); o.w = f2bf(acc.w);
      *(ushort4*)&xs[r * LDSW + l4] = o;
    }
  }
  // NO __syncthreads: all xs traffic is wave-local (wave w only touches rows
  // [w*16, w*16+16)); intra-wave LDS ordering is handled by waitcnt.

  // ---- phase B ----
  const int m = lane & 15, q = lane >> 4;
  const int rbase = row0 + wave * 16;

  bf16x8 a[4];
#pragma unroll
  for (int kc = 0; kc < 4; ++kc)
    a[kc] = *(const bf16x8*)&xs[(wave * 16 + m) * LDSW + kc * 32 + q * 8];

  f32x4 acc[16];
#pragma unroll
  for (int t = 0; t < 16; ++t) acc[t] = (f32x4){0.f, 0.f, 0.f, 0.f};

#pragma unroll
  for (int nt = 0; nt < 8; ++nt) {
    const unsigned short* pw = pkW + ((size_t)(nt * 4) * 64 + lane) * 8;
    const unsigned short* pr = pkR + ((size_t)(nt * 4) * 64 + lane) * 8;
#pragma unroll
    for (int kc = 0; kc < 4; ++kc) {
      bf16x8 bW = *(const bf16x8*)(pw + (size_t)kc * 64 * 8);
      acc[nt] = __builtin_amdgcn_mfma_f32_16x16x32_bf16(a[kc], bW, acc[nt], 0, 0, 0);
    }
#pragma unroll
    for (int kc = 0; kc < 4; ++kc) {
      bf16x8 bR = *(const bf16x8*)(pr + (size_t)kc * 64 * 8);
      acc[8 + nt] = __builtin_amdgcn_mfma_f32_16x16x32_bf16(a[kc], bR, acc[8 + nt], 0, 0, 0);
    }
  }

#pragma unroll
  for (int nt = 0; nt < 8; ++nt) {
    int col = nt * 16 + m;
    float bias = bv[col];
#pragma unroll
    for (int rg = 0; rg < 4; ++rg) {
      int row = rbase + q * 4 + rg;
      if (row < N_NODES) {
        hout[row * DIM + col] = f2bf(acc[nt][rg]);
        float v = acc[8 + nt][rg] + bias;
        if (LAST) skipf[row * DIM + col] = v;
        else      skipb[row * DIM + col] = f2bf(v);
      }
    }
  }
}

// ---------------- final aggregation: dlast = relu(dlast + gather(hwb)) --------

__global__ __launch_bounds__(256) void k_aggF(const unsigned short* __restrict__ hwb,
                                              const int* __restrict__ rowp,
                                              const int2* __restrict__ epk,
                                              float* __restrict__ actf) {
  int n = blockIdx.x * 8 + (threadIdx.x >> 5);
  if (n >= N_NODES) return;
  int l4 = (threadIdx.x & 31) * 4;
  float4 acc = make_float4(0.f, 0.f, 0.f, 0.f);
  int e0 = rowp[n], e1 = rowp[n + 1];
  for (int e = e0; e < e1; e += 4) {
    int4 p0 = *(const int4*)&epk[e];
    int4 p1 = *(const int4*)&epk[e + 2];
    ushort4 u0 = *(const ushort4*)&hwb[p0.x * DIM + l4];
    ushort4 u1 = *(const ushort4*)&hwb[p0.z * DIM + l4];
    ushort4 u2 = *(const ushort4*)&hwb[p1.x * DIM + l4];
    ushort4 u3 = *(const ushort4*)&hwb[p1.z * DIM + l4];
    float w0 = __int_as_float(p0.y), w1 = __int_as_float(p0.w);
    float w2 = __int_as_float(p1.y), w3 = __int_as_float(p1.w);
    acc.x = fmaf(w0, bf2f(u0.x), fmaf(w1, bf2f(u1.x), fmaf(w2, bf2f(u2.x), fmaf(w3, bf2f(u3.x), acc.x))));
    acc.y = fmaf(w0, bf2f(u0.y), fmaf(w1, bf2f(u1.y), fmaf(w2, bf2f(u2.y), fmaf(w3, bf2f(u3.y), acc.y))));
    acc.z = fmaf(w0, bf2f(u0.z), fmaf(w1, bf2f(u1.z), fmaf(w2, bf2f(u2.z), fmaf(w3, bf2f(u3.z), acc.z))));
    acc.w = fmaf(w0, bf2f(u0.w), fmaf(w1, bf2f(u1.w), fmaf(w2, bf2f(u2.w), fmaf(w3, bf2f(u3.w), acc.w))));
  }
  float4 s = *(const float4*)&actf[n * DIM + l4];
  acc.x = fmaxf(acc.x + s.x, 0.f);
  acc.y = fmaxf(acc.y + s.y, 0.f);
  acc.z = fmaxf(acc.z + s.z, 0.f);
  acc.w = fmaxf(acc.w + s.w, 0.f);
  *(float4*)&actf[n * DIM + l4] = acc;
}

// ---------------- global mean pool: block per graph, batch is SORTED ----------

__global__ __launch_bounds__(1024) void k_pool2(const float* __restrict__ h,
                                                const int* __restrict__ batch,
                                                float* __restrict__ pooled) {
  int g = blockIdx.x;
  int t = threadIdx.x;
  __shared__ int sb[2];
  if (t < 2) {
    int target = g + t;                 // lower_bound(batch, target)
    int lo = 0, hi = N_NODES;
    while (lo < hi) {
      int mid = (lo + hi) >> 1;
      if (batch[mid] < target) lo = mid + 1; else hi = mid;
    }
    sb[t] = lo;
  }
  __syncthreads();
  int start = sb[0], end = sb[1];
  int c = t & 127, rg = t >> 7;         // 8 row groups
  float acc = 0.f;
  for (int r = start + rg; r < end; r += 8) acc += h[r * DIM + c];
  __shared__ float sp[8][DIM];
  sp[rg][c] = acc;
  __syncthreads();
  if (rg == 0) {
    float tot = acc;
#pragma unroll
    for (int i = 1; i < 8; ++i) tot += sp[i][c];
    float cnt = fmaxf((float)(end - start), 1.f);
    pooled[g * DIM + c] = tot / cnt;
  }
}

// ---------------- MLP head ----------------

__global__ __launch_bounds__(128) void k_mlp1(const float* __restrict__ pooled,
                                              const float* __restrict__ w,
                                              const float* __restrict__ bias,
                                              float* __restrict__ g1) {
  int g = blockIdx.x, t = threadIdx.x;
  __shared__ float sp[DIM];
  sp[t] = pooled[g * DIM + t];
  __syncthreads();
  float acc = bias[t];
#pragma unroll 4
  for (int k = 0; k < DIM; ++k) acc = fmaf(sp[k], w[k * DIM + t], acc);
  g1[g * DIM + t] = fmaxf(acc, 0.f);
}

__global__ __launch_bounds__(128) void k_mlp2(const float* __restrict__ g1,
                                              const float* __restrict__ w,
                                              const float* __restrict__ bias,
                                              float* __restrict__ out) {
  int g = threadIdx.x;   // one thread per graph
  float l[N_CLASSES];
#pragma unroll
  for (int c = 0; c < N_CLASSES; ++c) l[c] = bias[c];
  for (int k = 0; k < DIM; ++k) {
    float gv = g1[g * DIM + k];
#pragma unroll
    for (int c = 0; c < N_CLASSES; ++c) l[c] = fmaf(gv, w[k * N_CLASSES + c], l[c]);
  }
  float m = l[0];
#pragma unroll
  for (int c = 1; c < N_CLASSES; ++c) m = fmaxf(m, l[c]);
  float s = 0.f;
#pragma unroll
  for (int c = 0; c < N_CLASSES; ++c) s += expf(l[c] - m);
  float lse = logf(s) + m;
#pragma unroll
  for (int c = 0; c < N_CLASSES; ++c) out[g * N_CLASSES + c] = l[c] - lse;
}

// ---------------- launch ----------------

extern "C" void kernel_launch(void* const* d_in, const int* in_sizes, int n_in,
                              void* d_out, int out_size, void* d_ws, size_t ws_size,
                              hipStream_t stream) {
  const float* x     = (const float*)d_in[0];
  const int* ei      = (const int*)d_in[1];     // int32 on device (harness)
  const int* batch   = (const int*)d_in[2];     // int32 on device (harness)
  const float* W1  = (const float*)d_in[3];
  const float* R1  = (const float*)d_in[4];
  const float* b1  = (const float*)d_in[5];
  const float* Wc  = (const float*)d_in[6];
  const float* Rc  = (const float*)d_in[7];
  const float* bc  = (const float*)d_in[8];
  const float* l1w = (const float*)d_in[9];
  const float* l1b = (const float*)d_in[10];
  const float* l2w = (const float*)d_in[11];
  const float* l2b = (const float*)d_in[12];

  float* out   = (float*)d_out;
  float* dlast = out + N_GRAPHS * N_CLASSES;   // 'last' region (fp32 layer-4 buffer)

  // workspace layout (float-word offsets), ~46 MB total:
  //   0         h0    (3,203,072 w : bf16 50048x128)
  //   3203072   h1    (3,203,072 w)
  //   6406144   skipb (3,203,072 w)
  //   9609216   deg   (50,000)   -- zero region start
  //   9659216   cnt   (50,000)
  //   9709216   epk   (1,600,000 w = 800,000 int2)  -- zero end (1,700,000 w)
  //   11309216  dinv  (50,000)
  //   11359216  rowp  (50,016)
  //   11409232  pooled(16,384)
  //   11425616  g1    (16,384)
  //   11442000  pk    (65,536 w)
  //   11507536  bsum  (256)
  //   11507792  boff  (256)
  float* ws = (float*)d_ws;
  unsigned short* h0    = (unsigned short*)ws;
  unsigned short* h1    = (unsigned short*)(ws + 3203072);
  unsigned short* skipb = (unsigned short*)(ws + 6406144);
  int*   deg   = (int*)(ws + 9609216);
  int*   cnt   = (int*)(ws + 9659216);
  int2*  epk   = (int2*)(ws + 9709216);
  float* dinv  = ws + 11309216;
  int*   rowp  = (int*)(ws + 11359216);
  float* pooled= ws + 11409232;
  float* g1    = ws + 11425616;
  unsigned short* pk = (unsigned short*)(ws + 11442000);
  int*   bsum  = (int*)(ws + 11507536);
  int*   boff  = (int*)(ws + 11507792);

  // CSR build (runs every launch; ws is re-poisoned by the harness)
  k_prep<<<NZB4 + 64, 256, 0, stream>>>((float4*)(ws + 9609216), W1, R1, Wc, Rc, pk);
  k_deg <<<(N_EDGES + 255) / 256, 256, 0, stream>>>(ei, deg);
  k_dinvsum<<<NB_SCAN, 256, 0, stream>>>(deg, dinv, bsum);
  k_bscan<<<1, 256, 0, stream>>>(bsum, boff, rowp);
  k_rowp<<<NB_SCAN, 256, 0, stream>>>(deg, boff, rowp);
  k_fill<<<(N_EDGES + 255) / 256, 256, 0, stream>>>(ei, rowp, cnt, dinv, epk);

  const int NGB = (N_NODES + 63) / 64;    // 782
  const int NAB = (N_NODES + 7) / 8;      // 6250

  // layer 1 gemm: x (fp32) -> h0, skipb
  k_gemm0<<<NGB, 256, 0, stream>>>(x, pk + 0 * 16384, pk + 4 * 16384, b1, h0, skipb);
  // fused [agg1 + gemm2]: h0,skipb -> h1, skipb
  k_aggemm<false><<<NGB, 256, 0, stream>>>(h0, rowp, epk,
      pk + 1 * 16384, pk + 5 * 16384, bc + 0 * DIM, h1, skipb, nullptr);
  // fused [agg2 + gemm3]: h1,skipb -> h0, skipb
  k_aggemm<false><<<NGB, 256, 0, stream>>>(h1, rowp, epk,
      pk + 2 * 16384, pk + 6 * 16384, bc + 1 * DIM, h0, skipb, nullptr);
  // fused [agg3 + gemm4]: h0,skipb -> h1, dlast (fp32 skip)
  k_aggemm<true><<<NGB, 256, 0, stream>>>(h0, rowp, epk,
      pk + 3 * 16384, pk + 7 * 16384, bc + 2 * DIM, h1, skipb, dlast);
  // final agg4: dlast = relu(dlast + gather(h1))
  k_aggF<<<NAB, 256, 0, stream>>>(h1, rowp, epk, dlast);

  k_pool2<<<N_GRAPHS, 1024, 0, stream>>>(dlast, batch, pooled);
  k_mlp1<<<N_GRAPHS, 128, 0, stream>>>(pooled, l1w, l1b, g1);
  k_mlp2<<<1, N_GRAPHS, 0, stream>>>(g1, l2w, l2b, out);
}